// Round 2
// baseline (850.829 us; speedup 1.0000x reference)
//
#include <hip/hip_runtime.h>

#define NN 100000
#define NE 1600000

__device__ __forceinline__ float wave_red(float v) {
#pragma unroll
    for (int off = 32; off > 0; off >>= 1) v += __shfl_down(v, off, 64);
    return v;
}

// XCD id (0..7), wave-uniform. [measured: learn_hip m09]
__device__ __forceinline__ unsigned get_xcc_id() {
    unsigned x;
    asm volatile("s_getreg_b32 %0, hwreg(HW_REG_XCC_ID)" : "=s"(x));
    return x & 7u;
}

// ---------------- edge block: MLP(19->16->2) + scatter-add + mean partials ----
// agg is 8 XCD-local replicas of [NN][2]; atomics are workgroup-scope so they
// execute (and stay) in the local XCD's L2 instead of fabric-level RMW.
template <bool NEED_SUM, bool WRITE_EOUT>
__global__ __launch_bounds__(256) void edge_kernel(
    const int* __restrict__ ei, const float* __restrict__ x,
    const float* __restrict__ eattr, const float* __restrict__ gptr,
    const float* __restrict__ W1, const float* __restrict__ B1,
    const float* __restrict__ W2, const float* __restrict__ B2,
    float* __restrict__ eout, float* __restrict__ agg, float* __restrict__ esum)
{
    __shared__ float sW1[19 * 16];
    __shared__ float sW2[16 * 2];
    __shared__ float sb1[16];
    __shared__ float sb2[2];
    for (int i = threadIdx.x; i < 304; i += 256) sW1[i] = W1[i];
    if (threadIdx.x < 32) sW2[threadIdx.x] = W2[threadIdx.x];
    if (threadIdx.x < 16) sb1[threadIdx.x] = B1[threadIdx.x];
    if (threadIdx.x < 2)  sb2[threadIdx.x] = B2[threadIdx.x];
    __syncthreads();

    float* myagg = agg + (size_t)get_xcc_id() * (NN * 2);

    int e = blockIdx.x * 256 + threadIdx.x;
    float o0 = 0.f, o1 = 0.f;
    if (e < NE) {
        int row = ei[e];
        int col = ei[NE + e];
        float in[19];
        in[0] = gptr[0];
        const float4* xr = reinterpret_cast<const float4*>(x + (size_t)row * 8);
        float4 a0 = xr[0], a1 = xr[1];
        in[1] = a0.x; in[2] = a0.y; in[3] = a0.z; in[4] = a0.w;
        in[5] = a1.x; in[6] = a1.y; in[7] = a1.z; in[8] = a1.w;
        const float4* xc = reinterpret_cast<const float4*>(x + (size_t)col * 8);
        float4 c0 = xc[0], c1 = xc[1];
        in[9] = c0.x; in[10] = c0.y; in[11] = c0.z; in[12] = c0.w;
        in[13] = c1.x; in[14] = c1.y; in[15] = c1.z; in[16] = c1.w;
        float2 ea = reinterpret_cast<const float2*>(eattr)[e];
        in[17] = ea.x; in[18] = ea.y;

        float h[16];
#pragma unroll
        for (int j = 0; j < 16; j++) h[j] = sb1[j];
#pragma unroll
        for (int k = 0; k < 19; k++) {
            float v = in[k];
            const float4* wr = reinterpret_cast<const float4*>(sW1 + k * 16);
            float4 w0 = wr[0], w1 = wr[1], w2 = wr[2], w3 = wr[3];
            h[0]  += v * w0.x; h[1]  += v * w0.y; h[2]  += v * w0.z; h[3]  += v * w0.w;
            h[4]  += v * w1.x; h[5]  += v * w1.y; h[6]  += v * w1.z; h[7]  += v * w1.w;
            h[8]  += v * w2.x; h[9]  += v * w2.y; h[10] += v * w2.z; h[11] += v * w2.w;
            h[12] += v * w3.x; h[13] += v * w3.y; h[14] += v * w3.z; h[15] += v * w3.w;
        }
        o0 = sb2[0]; o1 = sb2[1];
#pragma unroll
        for (int j = 0; j < 16; j++) {
            float hj = fmaxf(h[j], 0.f);
            o0 += hj * sW2[2 * j];
            o1 += hj * sW2[2 * j + 1];
        }
        if (WRITE_EOUT)
            reinterpret_cast<float2*>(eout)[e] = make_float2(o0, o1);
        float* dst = myagg + (size_t)row * 2;
        __hip_atomic_fetch_add(dst,     o0, __ATOMIC_RELAXED, __HIP_MEMORY_SCOPE_WORKGROUP);
        __hip_atomic_fetch_add(dst + 1, o1, __ATOMIC_RELAXED, __HIP_MEMORY_SCOPE_WORKGROUP);
    }
    if (NEED_SUM) {
        float r0 = wave_red(o0);
        float r1 = wave_red(o1);
        __shared__ float red[4][2];
        int wave = threadIdx.x >> 6, lane = threadIdx.x & 63;
        if (lane == 0) { red[wave][0] = r0; red[wave][1] = r1; }
        __syncthreads();
        if (threadIdx.x == 0) {
            float s0 = red[0][0] + red[1][0] + red[2][0] + red[3][0];
            float s1 = red[0][1] + red[1][1] + red[2][1] + red[3][1];
            atomicAdd(&esum[0], s0);   // few thousand only — agent scope fine
            atomicAdd(&esum[1], s1);
        }
    }
}

// ---------------- node block: MLP(11->16->8) + mean partials -----------------
template <bool NEED_SUM>
__global__ __launch_bounds__(256) void node_kernel(
    const float* __restrict__ x, const float* __restrict__ agg,
    const float* __restrict__ gptr,
    const float* __restrict__ W1, const float* __restrict__ B1,
    const float* __restrict__ W2, const float* __restrict__ B2,
    float* __restrict__ xout, float* __restrict__ nsum)
{
    __shared__ float sW1[11 * 16];
    __shared__ float sW2[16 * 8];
    __shared__ float sb1[16];
    __shared__ float sb2[8];
    if (threadIdx.x < 176) sW1[threadIdx.x] = W1[threadIdx.x];
    if (threadIdx.x < 128) sW2[threadIdx.x] = W2[threadIdx.x];
    if (threadIdx.x < 16) sb1[threadIdx.x] = B1[threadIdx.x];
    if (threadIdx.x < 8)  sb2[threadIdx.x] = B2[threadIdx.x];
    __syncthreads();

    int i = blockIdx.x * 256 + threadIdx.x;
    float out[8];
#pragma unroll
    for (int m = 0; m < 8; m++) out[m] = 0.f;

    if (i < NN) {
        float in[11];
        in[0] = gptr[0];
        const float4* xi = reinterpret_cast<const float4*>(x + (size_t)i * 8);
        float4 a0 = xi[0], a1 = xi[1];
        in[1] = a0.x; in[2] = a0.y; in[3] = a0.z; in[4] = a0.w;
        in[5] = a1.x; in[6] = a1.y; in[7] = a1.z; in[8] = a1.w;
        // sum the 8 XCD-local replicas
        float s0 = 0.f, s1 = 0.f;
#pragma unroll
        for (int r = 0; r < 8; r++) {
            float2 t = reinterpret_cast<const float2*>(agg + (size_t)r * (NN * 2))[i];
            s0 += t.x; s1 += t.y;
        }
        in[9] = s0; in[10] = s1;

        float h[16];
#pragma unroll
        for (int j = 0; j < 16; j++) h[j] = sb1[j];
#pragma unroll
        for (int k = 0; k < 11; k++) {
            float v = in[k];
            const float4* wr = reinterpret_cast<const float4*>(sW1 + k * 16);
            float4 w0 = wr[0], w1 = wr[1], w2 = wr[2], w3 = wr[3];
            h[0]  += v * w0.x; h[1]  += v * w0.y; h[2]  += v * w0.z; h[3]  += v * w0.w;
            h[4]  += v * w1.x; h[5]  += v * w1.y; h[6]  += v * w1.z; h[7]  += v * w1.w;
            h[8]  += v * w2.x; h[9]  += v * w2.y; h[10] += v * w2.z; h[11] += v * w2.w;
            h[12] += v * w3.x; h[13] += v * w3.y; h[14] += v * w3.z; h[15] += v * w3.w;
        }
#pragma unroll
        for (int m = 0; m < 8; m++) out[m] = sb2[m];
#pragma unroll
        for (int j = 0; j < 16; j++) {
            float hj = fmaxf(h[j], 0.f);
#pragma unroll
            for (int m = 0; m < 8; m++) out[m] += hj * sW2[j * 8 + m];
        }
        float4* xo = reinterpret_cast<float4*>(xout + (size_t)i * 8);
        xo[0] = make_float4(out[0], out[1], out[2], out[3]);
        xo[1] = make_float4(out[4], out[5], out[6], out[7]);
    }
    if (NEED_SUM) {
        float r[8];
#pragma unroll
        for (int m = 0; m < 8; m++) r[m] = wave_red(out[m]);
        __shared__ float red[4][8];
        int wave = threadIdx.x >> 6, lane = threadIdx.x & 63;
        if (lane == 0) {
#pragma unroll
            for (int m = 0; m < 8; m++) red[wave][m] = r[m];
        }
        __syncthreads();
        if (threadIdx.x == 0) {
#pragma unroll
            for (int m = 0; m < 8; m++) {
                float s = red[0][m] + red[1][m] + red[2][m] + red[3][m];
                atomicAdd(&nsum[m], s);
            }
        }
    }
}

// ---------------- global block: MLP(11->16->1), single thread ----------------
__global__ void glob_kernel(const float* __restrict__ esum, const float* __restrict__ nsum,
                            const float* __restrict__ gold,
                            const float* __restrict__ W1, const float* __restrict__ B1,
                            const float* __restrict__ W2, const float* __restrict__ B2,
                            float* __restrict__ gnew)
{
    if (threadIdx.x == 0 && blockIdx.x == 0) {
        float in[11];
#pragma unroll
        for (int j = 0; j < 8; j++) in[j] = nsum[j] * (1.0f / NN);
        in[8] = esum[0] * (1.0f / NE);
        in[9] = esum[1] * (1.0f / NE);
        in[10] = gold[0];
        float acc = B2[0];
#pragma unroll
        for (int j = 0; j < 16; j++) {
            float h = B1[j];
#pragma unroll
            for (int k = 0; k < 11; k++) h += in[k] * W1[k * 16 + j];
            acc += fmaxf(h, 0.f) * W2[j];
        }
        gnew[0] = acc;
    }
}

extern "C" void kernel_launch(void* const* d_in, const int* in_sizes, int n_in,
                              void* d_out, int out_size, void* d_ws, size_t ws_size,
                              hipStream_t stream) {
    const float* x     = (const float*)d_in[0];
    const int*   ei    = (const int*)d_in[1];
    const float* eattr = (const float*)d_in[2];
    const float* g     = (const float*)d_in[3];
    const float* eW1 = (const float*)d_in[4];
    const float* eB1 = (const float*)d_in[5];
    const float* eW2 = (const float*)d_in[6];
    const float* eB2 = (const float*)d_in[7];
    const float* nW1 = (const float*)d_in[8];
    const float* nB1 = (const float*)d_in[9];
    const float* nW2 = (const float*)d_in[10];
    const float* nB2 = (const float*)d_in[11];
    const float* gW1 = (const float*)d_in[12];
    const float* gB1 = (const float*)d_in[13];
    const float* gW2 = (const float*)d_in[14];
    const float* gB2 = (const float*)d_in[15];
    float* out = (float*)d_out;

    char* ws = (char*)d_ws;
    float* xb0 = (float*)(ws);                 // 3.2e6 B
    float* xb1 = (float*)(ws + 3200000);       // 3.2e6 B
    float* eb0 = (float*)(ws + 6400000);       // 12.8e6 B
    float* eb1 = (float*)(ws + 19200000);      // 12.8e6 B
    float* agg = (float*)(ws + 32000000);      // 8 XCD replicas x 100000*2 floats = 6.4e6 B
    float* esum = (float*)(ws + 38400000);     // 2 floats
    float* nsum = esum + 2;                    // 8 floats
    float* g1 = (float*)(ws + 38400064);
    float* g2 = g1 + 1;

    dim3 blk(256);
    dim3 egrid((NE + 255) / 256);
    dim3 ngrid((NN + 255) / 256);

    // ---- layer 0 ----
    hipMemsetAsync(agg, 0, 6400000 + 48, stream);
    edge_kernel<true, true><<<egrid, blk, 0, stream>>>(ei, x, eattr, g,
        eW1, eB1, eW2, eB2, eb0, agg, esum);
    node_kernel<true><<<ngrid, blk, 0, stream>>>(x, agg, g,
        nW1, nB1, nW2, nB2, xb0, nsum);
    glob_kernel<<<1, 64, 0, stream>>>(esum, nsum, g, gW1, gB1, gW2, gB2, g1);

    // ---- layer 1 ----
    hipMemsetAsync(agg, 0, 6400000 + 48, stream);
    edge_kernel<true, true><<<egrid, blk, 0, stream>>>(ei, xb0, eb0, g1,
        eW1 + 304, eB1 + 16, eW2 + 32, eB2 + 2, eb1, agg, esum);
    node_kernel<true><<<ngrid, blk, 0, stream>>>(xb0, agg, g1,
        nW1 + 176, nB1 + 16, nW2 + 128, nB2 + 8, xb1, nsum);
    glob_kernel<<<1, 64, 0, stream>>>(esum, nsum, g1, gW1 + 176, gB1 + 16, gW2 + 16, gB2 + 1, g2);

    // ---- layer 2 (no global block, no eout store; node output -> d_out) ----
    hipMemsetAsync(agg, 0, 6400000 + 48, stream);
    edge_kernel<false, false><<<egrid, blk, 0, stream>>>(ei, xb1, eb1, g2,
        eW1 + 608, eB1 + 32, eW2 + 64, eB2 + 4, nullptr, agg, esum);
    node_kernel<false><<<ngrid, blk, 0, stream>>>(xb1, agg, g2,
        nW1 + 352, nB1 + 32, nW2 + 256, nB2 + 16, out, nsum);
}

// Round 4
// 774.813 us; speedup vs baseline: 1.0981x; 1.0981x over previous
//
#include <hip/hip_runtime.h>

#define NN 100000
#define NE 1600000
#define CAP 48

__device__ __forceinline__ float wave_red(float v) {
#pragma unroll
    for (int off = 32; off > 0; off >>= 1) v += __shfl_down(v, off, 64);
    return v;
}

// ---------------- build: counting scatter (once per call) --------------------
__global__ __launch_bounds__(256) void build_kernel(
    const int* __restrict__ ei, int* __restrict__ cnt, int* __restrict__ slots)
{
    int e = blockIdx.x * 256 + threadIdx.x;
    if (e < NE) {
        int row = ei[e];
        int pos = atomicAdd(&cnt[row], 1);
        if (pos < CAP) slots[(size_t)row * CAP + pos] = e;
    }
}

// ---------------- edge block: MLP(19->16->2) + mean partials -----------------
template <bool NEED_SUM>
__global__ __launch_bounds__(256) void edge_kernel(
    const int* __restrict__ ei, const float* __restrict__ x,
    const float* __restrict__ eattr, const float* __restrict__ gptr,
    const float* __restrict__ W1, const float* __restrict__ B1,
    const float* __restrict__ W2, const float* __restrict__ B2,
    float* __restrict__ eout, float* __restrict__ esum)
{
    __shared__ float sW1[19 * 16];
    __shared__ float sW2[16 * 2];
    __shared__ float sb1[16];
    __shared__ float sb2[2];
    for (int i = threadIdx.x; i < 304; i += 256) sW1[i] = W1[i];
    if (threadIdx.x < 32) sW2[threadIdx.x] = W2[threadIdx.x];
    if (threadIdx.x < 16) sb1[threadIdx.x] = B1[threadIdx.x];
    if (threadIdx.x < 2)  sb2[threadIdx.x] = B2[threadIdx.x];
    __syncthreads();

    int e = blockIdx.x * 256 + threadIdx.x;
    float o0 = 0.f, o1 = 0.f;
    if (e < NE) {
        int row = ei[e];
        int col = ei[NE + e];
        float in[19];
        in[0] = gptr[0];
        const float4* xr = reinterpret_cast<const float4*>(x + (size_t)row * 8);
        float4 a0 = xr[0], a1 = xr[1];
        in[1] = a0.x; in[2] = a0.y; in[3] = a0.z; in[4] = a0.w;
        in[5] = a1.x; in[6] = a1.y; in[7] = a1.z; in[8] = a1.w;
        const float4* xc = reinterpret_cast<const float4*>(x + (size_t)col * 8);
        float4 c0 = xc[0], c1 = xc[1];
        in[9] = c0.x; in[10] = c0.y; in[11] = c0.z; in[12] = c0.w;
        in[13] = c1.x; in[14] = c1.y; in[15] = c1.z; in[16] = c1.w;
        float2 ea = reinterpret_cast<const float2*>(eattr)[e];
        in[17] = ea.x; in[18] = ea.y;

        float h[16];
#pragma unroll
        for (int j = 0; j < 16; j++) h[j] = sb1[j];
#pragma unroll
        for (int k = 0; k < 19; k++) {
            float v = in[k];
            const float4* wr = reinterpret_cast<const float4*>(sW1 + k * 16);
            float4 w0 = wr[0], w1 = wr[1], w2 = wr[2], w3 = wr[3];
            h[0]  += v * w0.x; h[1]  += v * w0.y; h[2]  += v * w0.z; h[3]  += v * w0.w;
            h[4]  += v * w1.x; h[5]  += v * w1.y; h[6]  += v * w1.z; h[7]  += v * w1.w;
            h[8]  += v * w2.x; h[9]  += v * w2.y; h[10] += v * w2.z; h[11] += v * w2.w;
            h[12] += v * w3.x; h[13] += v * w3.y; h[14] += v * w3.z; h[15] += v * w3.w;
        }
        o0 = sb2[0]; o1 = sb2[1];
#pragma unroll
        for (int j = 0; j < 16; j++) {
            float hj = fmaxf(h[j], 0.f);
            o0 += hj * sW2[2 * j];
            o1 += hj * sW2[2 * j + 1];
        }
        reinterpret_cast<float2*>(eout)[e] = make_float2(o0, o1);
    }
    if (NEED_SUM) {
        float r0 = wave_red(o0);
        float r1 = wave_red(o1);
        __shared__ float red[4][2];
        int wave = threadIdx.x >> 6, lane = threadIdx.x & 63;
        if (lane == 0) { red[wave][0] = r0; red[wave][1] = r1; }
        __syncthreads();
        if (threadIdx.x == 0) {
            float s0 = red[0][0] + red[1][0] + red[2][0] + red[3][0];
            float s1 = red[0][1] + red[1][1] + red[2][1] + red[3][1];
            atomicAdd(&esum[0], s0);   // ~6250 blocks only — negligible
            atomicAdd(&esum[1], s1);
        }
    }
}

// -------- node block: gather-aggregate + MLP(11->16->8) + mean partials ------
template <bool NEED_SUM>
__global__ __launch_bounds__(256) void node_kernel(
    const float* __restrict__ x, const float* __restrict__ eout,
    const int* __restrict__ cnt, const int* __restrict__ slots,
    const float* __restrict__ gptr,
    const float* __restrict__ W1, const float* __restrict__ B1,
    const float* __restrict__ W2, const float* __restrict__ B2,
    float* __restrict__ xout, float* __restrict__ nsum)
{
    __shared__ float sW1[11 * 16];
    __shared__ float sW2[16 * 8];
    __shared__ float sb1[16];
    __shared__ float sb2[8];
    if (threadIdx.x < 176) sW1[threadIdx.x] = W1[threadIdx.x];
    if (threadIdx.x < 128) sW2[threadIdx.x] = W2[threadIdx.x];
    if (threadIdx.x < 16) sb1[threadIdx.x] = B1[threadIdx.x];
    if (threadIdx.x < 8)  sb2[threadIdx.x] = B2[threadIdx.x];
    __syncthreads();

    int i = blockIdx.x * 256 + threadIdx.x;
    float out[8];
#pragma unroll
    for (int m = 0; m < 8; m++) out[m] = 0.f;

    if (i < NN) {
        float in[11];
        in[0] = gptr[0];
        const float4* xi = reinterpret_cast<const float4*>(x + (size_t)i * 8);
        float4 a0 = xi[0], a1 = xi[1];
        in[1] = a0.x; in[2] = a0.y; in[3] = a0.z; in[4] = a0.w;
        in[5] = a1.x; in[6] = a1.y; in[7] = a1.z; in[8] = a1.w;

        // gather-aggregate this node's edge embeddings
        int c = cnt[i]; if (c > CAP) c = CAP;
        const int* sl = slots + (size_t)i * CAP;
        const float2* e2 = reinterpret_cast<const float2*>(eout);
        float s0 = 0.f, s1 = 0.f;
        int j = 0;
        for (; j + 4 <= c; j += 4) {
            int i0 = sl[j], i1 = sl[j + 1], i2 = sl[j + 2], i3 = sl[j + 3];
            float2 v0 = e2[i0], v1 = e2[i1], v2 = e2[i2], v3 = e2[i3];
            s0 += v0.x + v1.x + v2.x + v3.x;
            s1 += v0.y + v1.y + v2.y + v3.y;
        }
        for (; j < c; j++) {
            float2 v = e2[sl[j]];
            s0 += v.x; s1 += v.y;
        }
        in[9] = s0; in[10] = s1;

        float h[16];
#pragma unroll
        for (int j2 = 0; j2 < 16; j2++) h[j2] = sb1[j2];
#pragma unroll
        for (int k = 0; k < 11; k++) {
            float v = in[k];
            const float4* wr = reinterpret_cast<const float4*>(sW1 + k * 16);
            float4 w0 = wr[0], w1 = wr[1], w2 = wr[2], w3 = wr[3];
            h[0]  += v * w0.x; h[1]  += v * w0.y; h[2]  += v * w0.z; h[3]  += v * w0.w;
            h[4]  += v * w1.x; h[5]  += v * w1.y; h[6]  += v * w1.z; h[7]  += v * w1.w;
            h[8]  += v * w2.x; h[9]  += v * w2.y; h[10] += v * w2.z; h[11] += v * w2.w;
            h[12] += v * w3.x; h[13] += v * w3.y; h[14] += v * w3.z; h[15] += v * w3.w;
        }
#pragma unroll
        for (int m = 0; m < 8; m++) out[m] = sb2[m];
#pragma unroll
        for (int j2 = 0; j2 < 16; j2++) {
            float hj = fmaxf(h[j2], 0.f);
#pragma unroll
            for (int m = 0; m < 8; m++) out[m] += hj * sW2[j2 * 8 + m];
        }
        float4* xo = reinterpret_cast<float4*>(xout + (size_t)i * 8);
        xo[0] = make_float4(out[0], out[1], out[2], out[3]);
        xo[1] = make_float4(out[4], out[5], out[6], out[7]);
    }
    if (NEED_SUM) {
        float r[8];
#pragma unroll
        for (int m = 0; m < 8; m++) r[m] = wave_red(out[m]);
        __shared__ float red[4][8];
        int wave = threadIdx.x >> 6, lane = threadIdx.x & 63;
        if (lane == 0) {
#pragma unroll
            for (int m = 0; m < 8; m++) red[wave][m] = r[m];
        }
        __syncthreads();
        if (threadIdx.x == 0) {
#pragma unroll
            for (int m = 0; m < 8; m++) {
                float s = red[0][m] + red[1][m] + red[2][m] + red[3][m];
                atomicAdd(&nsum[m], s);
            }
        }
    }
}

// ---------------- global block: MLP(11->16->1), single thread ----------------
__global__ void glob_kernel(const float* __restrict__ esum, const float* __restrict__ nsum,
                            const float* __restrict__ gold,
                            const float* __restrict__ W1, const float* __restrict__ B1,
                            const float* __restrict__ W2, const float* __restrict__ B2,
                            float* __restrict__ gnew)
{
    if (threadIdx.x == 0 && blockIdx.x == 0) {
        float in[11];
#pragma unroll
        for (int j = 0; j < 8; j++) in[j] = nsum[j] * (1.0f / NN);
        in[8] = esum[0] * (1.0f / NE);
        in[9] = esum[1] * (1.0f / NE);
        in[10] = gold[0];
        float acc = B2[0];
#pragma unroll
        for (int j = 0; j < 16; j++) {
            float h = B1[j];
#pragma unroll
            for (int k = 0; k < 11; k++) h += in[k] * W1[k * 16 + j];
            acc += fmaxf(h, 0.f) * W2[j];
        }
        gnew[0] = acc;
    }
}

extern "C" void kernel_launch(void* const* d_in, const int* in_sizes, int n_in,
                              void* d_out, int out_size, void* d_ws, size_t ws_size,
                              hipStream_t stream) {
    const float* x     = (const float*)d_in[0];
    const int*   ei    = (const int*)d_in[1];
    const float* eattr = (const float*)d_in[2];
    const float* g     = (const float*)d_in[3];
    const float* eW1 = (const float*)d_in[4];
    const float* eB1 = (const float*)d_in[5];
    const float* eW2 = (const float*)d_in[6];
    const float* eB2 = (const float*)d_in[7];
    const float* nW1 = (const float*)d_in[8];
    const float* nB1 = (const float*)d_in[9];
    const float* nW2 = (const float*)d_in[10];
    const float* nB2 = (const float*)d_in[11];
    const float* gW1 = (const float*)d_in[12];
    const float* gB1 = (const float*)d_in[13];
    const float* gW2 = (const float*)d_in[14];
    const float* gB2 = (const float*)d_in[15];
    float* out = (float*)d_out;

    char* ws = (char*)d_ws;
    float* xb0   = (float*)(ws);               // 3.2e6 B
    float* xb1   = (float*)(ws + 3200000);     // 3.2e6 B
    float* eb0   = (float*)(ws + 6400000);     // 12.8e6 B
    float* eb1   = (float*)(ws + 19200000);    // 12.8e6 B
    int*   cnt   = (int*)  (ws + 32000000);    // 4e5 B
    int*   slots = (int*)  (ws + 32400000);    // 100000*48*4 = 19.2e6 B
    float* esum  = (float*)(ws + 51600000);    // 2 floats
    float* nsum  = esum + 2;                   // 8 floats
    float* g1    = (float*)(ws + 51600064);
    float* g2    = g1 + 1;

    dim3 blk(256);
    dim3 egrid((NE + 255) / 256);
    dim3 ngrid((NN + 255) / 256);

    // ---- build CSR-lite (once per call) ----
    hipMemsetAsync(cnt, 0, 400000, stream);
    hipMemsetAsync(esum, 0, 48, stream);
    build_kernel<<<egrid, blk, 0, stream>>>(ei, cnt, slots);

    // ---- layer 0 ----
    edge_kernel<true><<<egrid, blk, 0, stream>>>(ei, x, eattr, g,
        eW1, eB1, eW2, eB2, eb0, esum);
    node_kernel<true><<<ngrid, blk, 0, stream>>>(x, eb0, cnt, slots, g,
        nW1, nB1, nW2, nB2, xb0, nsum);
    glob_kernel<<<1, 64, 0, stream>>>(esum, nsum, g, gW1, gB1, gW2, gB2, g1);

    // ---- layer 1 ----
    hipMemsetAsync(esum, 0, 48, stream);
    edge_kernel<true><<<egrid, blk, 0, stream>>>(ei, xb0, eb0, g1,
        eW1 + 304, eB1 + 16, eW2 + 32, eB2 + 2, eb1, esum);
    node_kernel<true><<<ngrid, blk, 0, stream>>>(xb0, eb1, cnt, slots, g1,
        nW1 + 176, nB1 + 16, nW2 + 128, nB2 + 8, xb1, nsum);
    glob_kernel<<<1, 64, 0, stream>>>(esum, nsum, g1, gW1 + 176, gB1 + 16, gW2 + 16, gB2 + 1, g2);

    // ---- layer 2 (no global block; node output -> d_out) ----
    edge_kernel<false><<<egrid, blk, 0, stream>>>(ei, xb1, eb1, g2,
        eW1 + 608, eB1 + 32, eW2 + 64, eB2 + 4, eb0, esum);
    node_kernel<false><<<ngrid, blk, 0, stream>>>(xb1, eb0, cnt, slots, g2,
        nW1 + 352, nB1 + 32, nW2 + 256, nB2 + 16, out, nsum);
}

// Round 5
// 724.678 us; speedup vs baseline: 1.1741x; 1.0692x over previous
//
#include <hip/hip_runtime.h>

#define NN 100000
#define NE 1600000
#define SCAN_B 1024
#define NBLK_SCAN ((NN + SCAN_B - 1) / SCAN_B)   // 98

__device__ __forceinline__ float wave_red(float v) {
#pragma unroll
    for (int off = 32; off > 0; off >>= 1) v += __shfl_down(v, off, 64);
    return v;
}

// ---------------- build phase (once per call) --------------------------------
// 1) count + per-edge position
__global__ __launch_bounds__(256) void build1_kernel(
    const int* __restrict__ ei, int* __restrict__ cnt, int* __restrict__ posArr)
{
    int e = blockIdx.x * 256 + threadIdx.x;
    if (e < NE) posArr[e] = atomicAdd(&cnt[ei[e]], 1);
}

// 2a) per-block sums of cnt
__global__ __launch_bounds__(SCAN_B) void scan1_kernel(
    const int* __restrict__ cnt, int* __restrict__ bsum)
{
    int i = blockIdx.x * SCAN_B + threadIdx.x;
    int v = (i < NN) ? cnt[i] : 0;
#pragma unroll
    for (int off = 32; off > 0; off >>= 1) v += __shfl_down(v, off, 64);
    __shared__ int wsum[16];
    int wave = threadIdx.x >> 6, lane = threadIdx.x & 63;
    if (lane == 0) wsum[wave] = v;
    __syncthreads();
    if (threadIdx.x == 0) {
        int s = 0;
#pragma unroll
        for (int w = 0; w < 16; w++) s += wsum[w];
        bsum[blockIdx.x] = s;
    }
}

// 2b) exclusive scan of the 98 block sums (tiny)
__global__ void scan2_kernel(const int* __restrict__ bsum, int* __restrict__ bexcl,
                             int* __restrict__ off)
{
    if (threadIdx.x == 0 && blockIdx.x == 0) {
        int s = 0;
        for (int b = 0; b < NBLK_SCAN; b++) { bexcl[b] = s; s += bsum[b]; }
        off[NN] = s;
    }
}

// 2c) per-block exclusive scan + base -> off[]
__global__ __launch_bounds__(SCAN_B) void scan3_kernel(
    const int* __restrict__ cnt, const int* __restrict__ bexcl, int* __restrict__ off)
{
    __shared__ int buf[2][SCAN_B];
    int t = threadIdx.x;
    int i = blockIdx.x * SCAN_B + t;
    int v = (i < NN) ? cnt[i] : 0;
    buf[0][t] = v;
    __syncthreads();
    int src = 0;
    for (int d = 1; d < SCAN_B; d <<= 1) {
        int nv = buf[src][t] + ((t >= d) ? buf[src][t - d] : 0);
        buf[src ^ 1][t] = nv;
        src ^= 1;
        __syncthreads();
    }
    if (i < NN) off[i] = bexcl[blockIdx.x] + buf[src][t] - v;   // exclusive
}

// 3) materialize row-sorted edge arrays
__global__ __launch_bounds__(256) void fill2_kernel(
    const int* __restrict__ ei, const int* __restrict__ posArr,
    const int* __restrict__ off, const float* __restrict__ eattr,
    int* __restrict__ row2, int* __restrict__ col2, float* __restrict__ ea2)
{
    int e = blockIdx.x * 256 + threadIdx.x;
    if (e < NE) {
        int row = ei[e];
        int j = off[row] + posArr[e];
        row2[j] = row;
        col2[j] = ei[NE + e];
        reinterpret_cast<float2*>(ea2)[j] =
            reinterpret_cast<const float2*>(eattr)[e];
    }
}

// ---------------- edge block: MLP(19->16->2), row-sorted order ---------------
template <bool NEED_SUM>
__global__ __launch_bounds__(256) void edge_kernel(
    const int* __restrict__ row2, const int* __restrict__ col2,
    const float* __restrict__ x, const float* __restrict__ eattrj,
    const float* __restrict__ gptr,
    const float* __restrict__ W1, const float* __restrict__ B1,
    const float* __restrict__ W2, const float* __restrict__ B2,
    float* __restrict__ eout, float* __restrict__ esum)
{
    __shared__ float sW1[19 * 16];
    __shared__ float sW2[16 * 2];
    __shared__ float sb1[16];
    __shared__ float sb2[2];
    for (int i = threadIdx.x; i < 304; i += 256) sW1[i] = W1[i];
    if (threadIdx.x < 32) sW2[threadIdx.x] = W2[threadIdx.x];
    if (threadIdx.x < 16) sb1[threadIdx.x] = B1[threadIdx.x];
    if (threadIdx.x < 2)  sb2[threadIdx.x] = B2[threadIdx.x];
    __syncthreads();

    int j = blockIdx.x * 256 + threadIdx.x;
    float o0 = 0.f, o1 = 0.f;
    if (j < NE) {
        int row = row2[j];
        int col = col2[j];
        float in[19];
        in[0] = gptr[0];
        const float4* xr = reinterpret_cast<const float4*>(x + (size_t)row * 8);
        float4 a0 = xr[0], a1 = xr[1];
        in[1] = a0.x; in[2] = a0.y; in[3] = a0.z; in[4] = a0.w;
        in[5] = a1.x; in[6] = a1.y; in[7] = a1.z; in[8] = a1.w;
        const float4* xc = reinterpret_cast<const float4*>(x + (size_t)col * 8);
        float4 c0 = xc[0], c1 = xc[1];
        in[9] = c0.x; in[10] = c0.y; in[11] = c0.z; in[12] = c0.w;
        in[13] = c1.x; in[14] = c1.y; in[15] = c1.z; in[16] = c1.w;
        float2 ea = reinterpret_cast<const float2*>(eattrj)[j];
        in[17] = ea.x; in[18] = ea.y;

        float h[16];
#pragma unroll
        for (int q = 0; q < 16; q++) h[q] = sb1[q];
#pragma unroll
        for (int k = 0; k < 19; k++) {
            float v = in[k];
            const float4* wr = reinterpret_cast<const float4*>(sW1 + k * 16);
            float4 w0 = wr[0], w1 = wr[1], w2 = wr[2], w3 = wr[3];
            h[0]  += v * w0.x; h[1]  += v * w0.y; h[2]  += v * w0.z; h[3]  += v * w0.w;
            h[4]  += v * w1.x; h[5]  += v * w1.y; h[6]  += v * w1.z; h[7]  += v * w1.w;
            h[8]  += v * w2.x; h[9]  += v * w2.y; h[10] += v * w2.z; h[11] += v * w2.w;
            h[12] += v * w3.x; h[13] += v * w3.y; h[14] += v * w3.z; h[15] += v * w3.w;
        }
        o0 = sb2[0]; o1 = sb2[1];
#pragma unroll
        for (int q = 0; q < 16; q++) {
            float hq = fmaxf(h[q], 0.f);
            o0 += hq * sW2[2 * q];
            o1 += hq * sW2[2 * q + 1];
        }
        reinterpret_cast<float2*>(eout)[j] = make_float2(o0, o1);
    }
    if (NEED_SUM) {
        float r0 = wave_red(o0);
        float r1 = wave_red(o1);
        __shared__ float red[4][2];
        int wave = threadIdx.x >> 6, lane = threadIdx.x & 63;
        if (lane == 0) { red[wave][0] = r0; red[wave][1] = r1; }
        __syncthreads();
        if (threadIdx.x == 0) {
            float s0 = red[0][0] + red[1][0] + red[2][0] + red[3][0];
            float s1 = red[0][1] + red[1][1] + red[2][1] + red[3][1];
            atomicAdd(&esum[0], s0);   // 6250 blocks only
            atomicAdd(&esum[1], s1);
        }
    }
}

// -------- node block: contiguous-range aggregate + MLP(11->16->8) ------------
template <bool NEED_SUM>
__global__ __launch_bounds__(256) void node_kernel(
    const float* __restrict__ x, const float* __restrict__ eout,
    const int* __restrict__ off, const float* __restrict__ gptr,
    const float* __restrict__ W1, const float* __restrict__ B1,
    const float* __restrict__ W2, const float* __restrict__ B2,
    float* __restrict__ xout, float* __restrict__ nsum)
{
    __shared__ float sW1[11 * 16];
    __shared__ float sW2[16 * 8];
    __shared__ float sb1[16];
    __shared__ float sb2[8];
    if (threadIdx.x < 176) sW1[threadIdx.x] = W1[threadIdx.x];
    if (threadIdx.x < 128) sW2[threadIdx.x] = W2[threadIdx.x];
    if (threadIdx.x < 16) sb1[threadIdx.x] = B1[threadIdx.x];
    if (threadIdx.x < 8)  sb2[threadIdx.x] = B2[threadIdx.x];
    __syncthreads();

    int i = blockIdx.x * 256 + threadIdx.x;
    float out[8];
#pragma unroll
    for (int m = 0; m < 8; m++) out[m] = 0.f;

    if (i < NN) {
        float in[11];
        in[0] = gptr[0];
        const float4* xi = reinterpret_cast<const float4*>(x + (size_t)i * 8);
        float4 a0 = xi[0], a1 = xi[1];
        in[1] = a0.x; in[2] = a0.y; in[3] = a0.z; in[4] = a0.w;
        in[5] = a1.x; in[6] = a1.y; in[7] = a1.z; in[8] = a1.w;

        // contiguous aggregate over this node's sorted edge range
        int b0 = off[i], b1 = off[i + 1];
        const float2* e2 = reinterpret_cast<const float2*>(eout);
        const float4* e4 = reinterpret_cast<const float4*>(eout);
        float s0 = 0.f, s1 = 0.f;
        int j = b0;
        if ((j & 1) && j < b1) { float2 v = e2[j]; s0 += v.x; s1 += v.y; j++; }
        for (; j + 2 <= b1; j += 2) {
            float4 v = e4[j >> 1];
            s0 += v.x + v.z; s1 += v.y + v.w;
        }
        if (j < b1) { float2 v = e2[j]; s0 += v.x; s1 += v.y; }
        in[9] = s0; in[10] = s1;

        float h[16];
#pragma unroll
        for (int q = 0; q < 16; q++) h[q] = sb1[q];
#pragma unroll
        for (int k = 0; k < 11; k++) {
            float v = in[k];
            const float4* wr = reinterpret_cast<const float4*>(sW1 + k * 16);
            float4 w0 = wr[0], w1 = wr[1], w2 = wr[2], w3 = wr[3];
            h[0]  += v * w0.x; h[1]  += v * w0.y; h[2]  += v * w0.z; h[3]  += v * w0.w;
            h[4]  += v * w1.x; h[5]  += v * w1.y; h[6]  += v * w1.z; h[7]  += v * w1.w;
            h[8]  += v * w2.x; h[9]  += v * w2.y; h[10] += v * w2.z; h[11] += v * w2.w;
            h[12] += v * w3.x; h[13] += v * w3.y; h[14] += v * w3.z; h[15] += v * w3.w;
        }
#pragma unroll
        for (int m = 0; m < 8; m++) out[m] = sb2[m];
#pragma unroll
        for (int q = 0; q < 16; q++) {
            float hq = fmaxf(h[q], 0.f);
#pragma unroll
            for (int m = 0; m < 8; m++) out[m] += hq * sW2[q * 8 + m];
        }
        float4* xo = reinterpret_cast<float4*>(xout + (size_t)i * 8);
        xo[0] = make_float4(out[0], out[1], out[2], out[3]);
        xo[1] = make_float4(out[4], out[5], out[6], out[7]);
    }
    if (NEED_SUM) {
        float r[8];
#pragma unroll
        for (int m = 0; m < 8; m++) r[m] = wave_red(out[m]);
        __shared__ float red[4][8];
        int wave = threadIdx.x >> 6, lane = threadIdx.x & 63;
        if (lane == 0) {
#pragma unroll
            for (int m = 0; m < 8; m++) red[wave][m] = r[m];
        }
        __syncthreads();
        if (threadIdx.x == 0) {
#pragma unroll
            for (int m = 0; m < 8; m++) {
                float s = red[0][m] + red[1][m] + red[2][m] + red[3][m];
                atomicAdd(&nsum[m], s);
            }
        }
    }
}

// ---------------- global block: MLP(11->16->1), single thread ----------------
__global__ void glob_kernel(const float* __restrict__ esum, const float* __restrict__ nsum,
                            const float* __restrict__ gold,
                            const float* __restrict__ W1, const float* __restrict__ B1,
                            const float* __restrict__ W2, const float* __restrict__ B2,
                            float* __restrict__ gnew)
{
    if (threadIdx.x == 0 && blockIdx.x == 0) {
        float in[11];
#pragma unroll
        for (int j = 0; j < 8; j++) in[j] = nsum[j] * (1.0f / NN);
        in[8] = esum[0] * (1.0f / NE);
        in[9] = esum[1] * (1.0f / NE);
        in[10] = gold[0];
        float acc = B2[0];
#pragma unroll
        for (int j = 0; j < 16; j++) {
            float h = B1[j];
#pragma unroll
            for (int k = 0; k < 11; k++) h += in[k] * W1[k * 16 + j];
            acc += fmaxf(h, 0.f) * W2[j];
        }
        gnew[0] = acc;
    }
}

extern "C" void kernel_launch(void* const* d_in, const int* in_sizes, int n_in,
                              void* d_out, int out_size, void* d_ws, size_t ws_size,
                              hipStream_t stream) {
    const float* x     = (const float*)d_in[0];
    const int*   ei    = (const int*)d_in[1];
    const float* eattr = (const float*)d_in[2];
    const float* g     = (const float*)d_in[3];
    const float* eW1 = (const float*)d_in[4];
    const float* eB1 = (const float*)d_in[5];
    const float* eW2 = (const float*)d_in[6];
    const float* eB2 = (const float*)d_in[7];
    const float* nW1 = (const float*)d_in[8];
    const float* nB1 = (const float*)d_in[9];
    const float* nW2 = (const float*)d_in[10];
    const float* nB2 = (const float*)d_in[11];
    const float* gW1 = (const float*)d_in[12];
    const float* gB1 = (const float*)d_in[13];
    const float* gW2 = (const float*)d_in[14];
    const float* gB2 = (const float*)d_in[15];
    float* out = (float*)d_out;

    char* ws = (char*)d_ws;
    float* xb0    = (float*)(ws);               // 3.2e6 B
    float* xb1    = (float*)(ws + 3200000);     // 3.2e6 B
    float* eb0    = (float*)(ws + 6400000);     // 12.8e6 B
    float* eb1    = (float*)(ws + 19200000);    // 12.8e6 B (aliases ea2: dead after L0 edge)
    float* ea2    = eb1;
    int*   cnt    = (int*)  (ws + 32000000);    // 4e5 B
    int*   posArr = (int*)  (ws + 32400000);    // 6.4e6 B
    int*   off    = (int*)  (ws + 38800000);    // (NN+1)*4 = 400004 B
    int*   bsum   = (int*)  (ws + 39200016);    // 392 B
    int*   bexcl  = (int*)  (ws + 39200416);    // 392 B
    int*   row2   = (int*)  (ws + 39200832);    // 6.4e6 B
    int*   col2   = (int*)  (ws + 45600832);    // 6.4e6 B
    float* esum   = (float*)(ws + 52000832);    // 2 floats
    float* nsum   = esum + 2;                   // 8 floats
    float* g1     = (float*)(ws + 52000896);
    float* g2     = g1 + 1;

    dim3 blk(256);
    dim3 egrid((NE + 255) / 256);               // 6250
    dim3 ngrid((NN + 255) / 256);               // 391

    // ---- build row-sorted CSR (once per call) ----
    hipMemsetAsync(cnt, 0, 400000, stream);
    hipMemsetAsync(esum, 0, 48, stream);
    build1_kernel<<<egrid, blk, 0, stream>>>(ei, cnt, posArr);
    scan1_kernel<<<NBLK_SCAN, SCAN_B, 0, stream>>>(cnt, bsum);
    scan2_kernel<<<1, 64, 0, stream>>>(bsum, bexcl, off);
    scan3_kernel<<<NBLK_SCAN, SCAN_B, 0, stream>>>(cnt, bexcl, off);
    fill2_kernel<<<egrid, blk, 0, stream>>>(ei, posArr, off, eattr, row2, col2, ea2);

    // ---- layer 0 ----
    edge_kernel<true><<<egrid, blk, 0, stream>>>(row2, col2, x, ea2, g,
        eW1, eB1, eW2, eB2, eb0, esum);
    node_kernel<true><<<ngrid, blk, 0, stream>>>(x, eb0, off, g,
        nW1, nB1, nW2, nB2, xb0, nsum);
    glob_kernel<<<1, 64, 0, stream>>>(esum, nsum, g, gW1, gB1, gW2, gB2, g1);

    // ---- layer 1 ----
    hipMemsetAsync(esum, 0, 48, stream);
    edge_kernel<true><<<egrid, blk, 0, stream>>>(row2, col2, xb0, eb0, g1,
        eW1 + 304, eB1 + 16, eW2 + 32, eB2 + 2, eb1, esum);
    node_kernel<true><<<ngrid, blk, 0, stream>>>(xb0, eb1, off, g1,
        nW1 + 176, nB1 + 16, nW2 + 128, nB2 + 8, xb1, nsum);
    glob_kernel<<<1, 64, 0, stream>>>(esum, nsum, g1, gW1 + 176, gB1 + 16, gW2 + 16, gB2 + 1, g2);

    // ---- layer 2 (no global block; node output -> d_out) ----
    edge_kernel<false><<<egrid, blk, 0, stream>>>(row2, col2, xb1, eb1, g2,
        eW1 + 608, eB1 + 32, eW2 + 64, eB2 + 4, eb0, esum);
    node_kernel<false><<<ngrid, blk, 0, stream>>>(xb1, eb0, off, g2,
        nW1 + 352, nB1 + 32, nW2 + 256, nB2 + 16, out, nsum);
}

// Round 6
// 550.539 us; speedup vs baseline: 1.5454x; 1.3163x over previous
//
#include <hip/hip_runtime.h>

#define NN 100000
#define NE 1600000
#define NEH (NE / 2)
#define SCAN_B 1024
#define NBLK_SCAN ((NN + SCAN_B - 1) / SCAN_B)   // 98

__device__ __forceinline__ float wave_red(float v) {
#pragma unroll
    for (int off = 32; off > 0; off >>= 1) v += __shfl_down(v, off, 64);
    return v;
}

// ---------------- build phase (once per call) --------------------------------
__global__ __launch_bounds__(256) void build1_kernel(
    const int* __restrict__ ei, int* __restrict__ cnt, int* __restrict__ posArr)
{
    int e = blockIdx.x * 256 + threadIdx.x;
    if (e < NE) posArr[e] = atomicAdd(&cnt[ei[e]], 1);
}

__global__ __launch_bounds__(SCAN_B) void scan1_kernel(
    const int* __restrict__ cnt, int* __restrict__ bsum)
{
    int i = blockIdx.x * SCAN_B + threadIdx.x;
    int v = (i < NN) ? cnt[i] : 0;
#pragma unroll
    for (int off = 32; off > 0; off >>= 1) v += __shfl_down(v, off, 64);
    __shared__ int wsum[16];
    int wave = threadIdx.x >> 6, lane = threadIdx.x & 63;
    if (lane == 0) wsum[wave] = v;
    __syncthreads();
    if (threadIdx.x == 0) {
        int s = 0;
#pragma unroll
        for (int w = 0; w < 16; w++) s += wsum[w];
        bsum[blockIdx.x] = s;
    }
}

__global__ void scan2_kernel(const int* __restrict__ bsum, int* __restrict__ bexcl,
                             int* __restrict__ off)
{
    if (threadIdx.x == 0 && blockIdx.x == 0) {
        int s = 0;
        for (int b = 0; b < NBLK_SCAN; b++) { bexcl[b] = s; s += bsum[b]; }
        off[NN] = s;
    }
}

__global__ __launch_bounds__(SCAN_B) void scan3_kernel(
    const int* __restrict__ cnt, const int* __restrict__ bexcl, int* __restrict__ off)
{
    __shared__ int buf[2][SCAN_B];
    int t = threadIdx.x;
    int i = blockIdx.x * SCAN_B + t;
    int v = (i < NN) ? cnt[i] : 0;
    buf[0][t] = v;
    __syncthreads();
    int src = 0;
    for (int d = 1; d < SCAN_B; d <<= 1) {
        int nv = buf[src][t] + ((t >= d) ? buf[src][t - d] : 0);
        buf[src ^ 1][t] = nv;
        src ^= 1;
        __syncthreads();
    }
    if (i < NN) off[i] = bexcl[blockIdx.x] + buf[src][t] - v;   // exclusive
}

__global__ __launch_bounds__(256) void fill2_kernel(
    const int* __restrict__ ei, const int* __restrict__ posArr,
    const int* __restrict__ off, const float* __restrict__ eattr,
    int* __restrict__ row2, int* __restrict__ col2, float* __restrict__ ea2)
{
    int e = blockIdx.x * 256 + threadIdx.x;
    if (e < NE) {
        int row = ei[e];
        int j = off[row] + posArr[e];
        row2[j] = row;
        col2[j] = ei[NE + e];
        reinterpret_cast<float2*>(ea2)[j] =
            reinterpret_cast<const float2*>(eattr)[e];
    }
}

// ---------------- edge block: MLP(19->16->2), 2 edges/thread -----------------
// Weights read via uniform (scalar) path — no LDS staging at all.
template <bool NEED_SUM>
__global__ __launch_bounds__(256) void edge_kernel(
    const int* __restrict__ row2, const int* __restrict__ col2,
    const float* __restrict__ x, const float* __restrict__ eattrj,
    const float* __restrict__ gptr,
    const float* __restrict__ W1, const float* __restrict__ B1,
    const float* __restrict__ W2, const float* __restrict__ B2,
    float* __restrict__ eout, float* __restrict__ esum)
{
    int j0 = blockIdx.x * 256 + threadIdx.x;     // 0..NEH-1, grid exact
    int j1 = j0 + NEH;

    float gval = gptr[0];

    int rowA = row2[j0], colA = col2[j0];
    int rowB = row2[j1], colB = col2[j1];

    float inA[19], inB[19];
    inA[0] = gval; inB[0] = gval;
    {
        const float4* p = reinterpret_cast<const float4*>(x + (size_t)rowA * 8);
        float4 a0 = p[0], a1 = p[1];
        inA[1] = a0.x; inA[2] = a0.y; inA[3] = a0.z; inA[4] = a0.w;
        inA[5] = a1.x; inA[6] = a1.y; inA[7] = a1.z; inA[8] = a1.w;
    }
    {
        const float4* p = reinterpret_cast<const float4*>(x + (size_t)colA * 8);
        float4 a0 = p[0], a1 = p[1];
        inA[9] = a0.x; inA[10] = a0.y; inA[11] = a0.z; inA[12] = a0.w;
        inA[13] = a1.x; inA[14] = a1.y; inA[15] = a1.z; inA[16] = a1.w;
    }
    {
        const float4* p = reinterpret_cast<const float4*>(x + (size_t)rowB * 8);
        float4 a0 = p[0], a1 = p[1];
        inB[1] = a0.x; inB[2] = a0.y; inB[3] = a0.z; inB[4] = a0.w;
        inB[5] = a1.x; inB[6] = a1.y; inB[7] = a1.z; inB[8] = a1.w;
    }
    {
        const float4* p = reinterpret_cast<const float4*>(x + (size_t)colB * 8);
        float4 a0 = p[0], a1 = p[1];
        inB[9] = a0.x; inB[10] = a0.y; inB[11] = a0.z; inB[12] = a0.w;
        inB[13] = a1.x; inB[14] = a1.y; inB[15] = a1.z; inB[16] = a1.w;
    }
    {
        float2 ea = reinterpret_cast<const float2*>(eattrj)[j0];
        inA[17] = ea.x; inA[18] = ea.y;
        float2 eb = reinterpret_cast<const float2*>(eattrj)[j1];
        inB[17] = eb.x; inB[18] = eb.y;
    }

    float hA[16], hB[16];
#pragma unroll
    for (int q = 0; q < 16; q++) { float b = B1[q]; hA[q] = b; hB[q] = b; }
#pragma unroll
    for (int k = 0; k < 19; k++) {
        float vA = inA[k], vB = inB[k];
#pragma unroll
        for (int q = 0; q < 16; q++) {
            float w = W1[k * 16 + q];          // uniform -> s_load + K$ broadcast
            hA[q] += vA * w;
            hB[q] += vB * w;
        }
    }
    float oA0 = B2[0], oA1 = B2[1], oB0 = B2[0], oB1 = B2[1];
#pragma unroll
    for (int q = 0; q < 16; q++) {
        float w0 = W2[2 * q], w1 = W2[2 * q + 1];
        float a = fmaxf(hA[q], 0.f);
        float b = fmaxf(hB[q], 0.f);
        oA0 += a * w0; oA1 += a * w1;
        oB0 += b * w0; oB1 += b * w1;
    }
    reinterpret_cast<float2*>(eout)[j0] = make_float2(oA0, oA1);
    reinterpret_cast<float2*>(eout)[j1] = make_float2(oB0, oB1);

    if (NEED_SUM) {
        float r0 = wave_red(oA0 + oB0);
        float r1 = wave_red(oA1 + oB1);
        __shared__ float red[4][2];
        int wave = threadIdx.x >> 6, lane = threadIdx.x & 63;
        if (lane == 0) { red[wave][0] = r0; red[wave][1] = r1; }
        __syncthreads();
        if (threadIdx.x == 0) {
            float s0 = red[0][0] + red[1][0] + red[2][0] + red[3][0];
            float s1 = red[0][1] + red[1][1] + red[2][1] + red[3][1];
            atomicAdd(&esum[0], s0);   // 3125 blocks only
            atomicAdd(&esum[1], s1);
        }
    }
}

// -------- node block: contiguous-range aggregate + MLP(11->16->8) ------------
template <bool NEED_SUM>
__global__ __launch_bounds__(256) void node_kernel(
    const float* __restrict__ x, const float* __restrict__ eout,
    const int* __restrict__ off, const float* __restrict__ gptr,
    const float* __restrict__ W1, const float* __restrict__ B1,
    const float* __restrict__ W2, const float* __restrict__ B2,
    float* __restrict__ xout, float* __restrict__ nsum)
{
    int i = blockIdx.x * 256 + threadIdx.x;
    float out[8];
#pragma unroll
    for (int m = 0; m < 8; m++) out[m] = 0.f;

    if (i < NN) {
        float in[11];
        in[0] = gptr[0];
        const float4* xi = reinterpret_cast<const float4*>(x + (size_t)i * 8);
        float4 a0 = xi[0], a1 = xi[1];
        in[1] = a0.x; in[2] = a0.y; in[3] = a0.z; in[4] = a0.w;
        in[5] = a1.x; in[6] = a1.y; in[7] = a1.z; in[8] = a1.w;

        int b0 = off[i], b1 = off[i + 1];
        const float2* e2 = reinterpret_cast<const float2*>(eout);
        const float4* e4 = reinterpret_cast<const float4*>(eout);
        float s0 = 0.f, s1 = 0.f;
        int j = b0;
        if ((j & 1) && j < b1) { float2 v = e2[j]; s0 += v.x; s1 += v.y; j++; }
        for (; j + 2 <= b1; j += 2) {
            float4 v = e4[j >> 1];
            s0 += v.x + v.z; s1 += v.y + v.w;
        }
        if (j < b1) { float2 v = e2[j]; s0 += v.x; s1 += v.y; }
        in[9] = s0; in[10] = s1;

        float h[16];
#pragma unroll
        for (int q = 0; q < 16; q++) h[q] = B1[q];
#pragma unroll
        for (int k = 0; k < 11; k++) {
            float v = in[k];
#pragma unroll
            for (int q = 0; q < 16; q++) h[q] += v * W1[k * 16 + q];   // scalar path
        }
#pragma unroll
        for (int m = 0; m < 8; m++) out[m] = B2[m];
#pragma unroll
        for (int q = 0; q < 16; q++) {
            float hq = fmaxf(h[q], 0.f);
#pragma unroll
            for (int m = 0; m < 8; m++) out[m] += hq * W2[q * 8 + m];
        }
        float4* xo = reinterpret_cast<float4*>(xout + (size_t)i * 8);
        xo[0] = make_float4(out[0], out[1], out[2], out[3]);
        xo[1] = make_float4(out[4], out[5], out[6], out[7]);
    }
    if (NEED_SUM) {
        float r[8];
#pragma unroll
        for (int m = 0; m < 8; m++) r[m] = wave_red(out[m]);
        __shared__ float red[4][8];
        int wave = threadIdx.x >> 6, lane = threadIdx.x & 63;
        if (lane == 0) {
#pragma unroll
            for (int m = 0; m < 8; m++) red[wave][m] = r[m];
        }
        __syncthreads();
        if (threadIdx.x == 0) {
#pragma unroll
            for (int m = 0; m < 8; m++) {
                float s = red[0][m] + red[1][m] + red[2][m] + red[3][m];
                atomicAdd(&nsum[m], s);
            }
        }
    }
}

// ---------------- global block: MLP(11->16->1), single thread ----------------
__global__ void glob_kernel(const float* __restrict__ esum, const float* __restrict__ nsum,
                            const float* __restrict__ gold,
                            const float* __restrict__ W1, const float* __restrict__ B1,
                            const float* __restrict__ W2, const float* __restrict__ B2,
                            float* __restrict__ gnew)
{
    if (threadIdx.x == 0 && blockIdx.x == 0) {
        float in[11];
#pragma unroll
        for (int j = 0; j < 8; j++) in[j] = nsum[j] * (1.0f / NN);
        in[8] = esum[0] * (1.0f / NE);
        in[9] = esum[1] * (1.0f / NE);
        in[10] = gold[0];
        float acc = B2[0];
#pragma unroll
        for (int j = 0; j < 16; j++) {
            float h = B1[j];
#pragma unroll
            for (int k = 0; k < 11; k++) h += in[k] * W1[k * 16 + j];
            acc += fmaxf(h, 0.f) * W2[j];
        }
        gnew[0] = acc;
    }
}

extern "C" void kernel_launch(void* const* d_in, const int* in_sizes, int n_in,
                              void* d_out, int out_size, void* d_ws, size_t ws_size,
                              hipStream_t stream) {
    const float* x     = (const float*)d_in[0];
    const int*   ei    = (const int*)d_in[1];
    const float* eattr = (const float*)d_in[2];
    const float* g     = (const float*)d_in[3];
    const float* eW1 = (const float*)d_in[4];
    const float* eB1 = (const float*)d_in[5];
    const float* eW2 = (const float*)d_in[6];
    const float* eB2 = (const float*)d_in[7];
    const float* nW1 = (const float*)d_in[8];
    const float* nB1 = (const float*)d_in[9];
    const float* nW2 = (const float*)d_in[10];
    const float* nB2 = (const float*)d_in[11];
    const float* gW1 = (const float*)d_in[12];
    const float* gB1 = (const float*)d_in[13];
    const float* gW2 = (const float*)d_in[14];
    const float* gB2 = (const float*)d_in[15];
    float* out = (float*)d_out;

    char* ws = (char*)d_ws;
    float* xb0    = (float*)(ws);               // 3.2e6 B
    float* xb1    = (float*)(ws + 3200000);     // 3.2e6 B
    float* eb0    = (float*)(ws + 6400000);     // 12.8e6 B
    float* eb1    = (float*)(ws + 19200000);    // 12.8e6 B (aliases ea2: dead after L0 edge)
    float* ea2    = eb1;
    int*   cnt    = (int*)  (ws + 32000000);    // 4e5 B
    int*   posArr = (int*)  (ws + 32400000);    // 6.4e6 B
    int*   off    = (int*)  (ws + 38800000);    // (NN+1)*4 B
    int*   bsum   = (int*)  (ws + 39200016);
    int*   bexcl  = (int*)  (ws + 39200416);
    int*   row2   = (int*)  (ws + 39200832);    // 6.4e6 B
    int*   col2   = (int*)  (ws + 45600832);    // 6.4e6 B
    float* esum   = (float*)(ws + 52000832);
    float* nsum   = esum + 2;
    float* g1     = (float*)(ws + 52000896);
    float* g2     = g1 + 1;

    dim3 blk(256);
    dim3 egrid(NE / 256);                       // 6250 (build/fill)
    dim3 e2grid(NEH / 256);                     // 3125 (edge MLP, 2 edges/thread)
    dim3 ngrid((NN + 255) / 256);               // 391

    // ---- build row-sorted CSR (once per call) ----
    hipMemsetAsync(cnt, 0, 400000, stream);
    hipMemsetAsync(esum, 0, 48, stream);
    build1_kernel<<<egrid, blk, 0, stream>>>(ei, cnt, posArr);
    scan1_kernel<<<NBLK_SCAN, SCAN_B, 0, stream>>>(cnt, bsum);
    scan2_kernel<<<1, 64, 0, stream>>>(bsum, bexcl, off);
    scan3_kernel<<<NBLK_SCAN, SCAN_B, 0, stream>>>(cnt, bexcl, off);
    fill2_kernel<<<egrid, blk, 0, stream>>>(ei, posArr, off, eattr, row2, col2, ea2);

    // ---- layer 0 ----
    edge_kernel<true><<<e2grid, blk, 0, stream>>>(row2, col2, x, ea2, g,
        eW1, eB1, eW2, eB2, eb0, esum);
    node_kernel<true><<<ngrid, blk, 0, stream>>>(x, eb0, off, g,
        nW1, nB1, nW2, nB2, xb0, nsum);
    glob_kernel<<<1, 64, 0, stream>>>(esum, nsum, g, gW1, gB1, gW2, gB2, g1);

    // ---- layer 1 ----
    hipMemsetAsync(esum, 0, 48, stream);
    edge_kernel<true><<<e2grid, blk, 0, stream>>>(row2, col2, xb0, eb0, g1,
        eW1 + 304, eB1 + 16, eW2 + 32, eB2 + 2, eb1, esum);
    node_kernel<true><<<ngrid, blk, 0, stream>>>(xb0, eb1, off, g1,
        nW1 + 176, nB1 + 16, nW2 + 128, nB2 + 8, xb1, nsum);
    glob_kernel<<<1, 64, 0, stream>>>(esum, nsum, g1, gW1 + 176, gB1 + 16, gW2 + 16, gB2 + 1, g2);

    // ---- layer 2 (no global block; node output -> d_out) ----
    edge_kernel<false><<<e2grid, blk, 0, stream>>>(row2, col2, xb1, eb1, g2,
        eW1 + 608, eB1 + 32, eW2 + 64, eB2 + 4, eb0, esum);
    node_kernel<false><<<ngrid, blk, 0, stream>>>(xb1, eb0, off, g2,
        nW1 + 352, nB1 + 32, nW2 + 256, nB2 + 16, out, nsum);
}

// Round 8
// 527.564 us; speedup vs baseline: 1.6128x; 1.0435x over previous
//
#include <hip/hip_runtime.h>

#define NN 100000
#define NE 1600000
#define NEH (NE / 2)                             // 800000
#define SCAN_B 1024
#define NBLK_SCAN ((NN + SCAN_B - 1) / SCAN_B)   // 98

__device__ __forceinline__ float wave_red(float v) {
#pragma unroll
    for (int off = 32; off > 0; off >>= 1) v += __shfl_down(v, off, 64);
    return v;
}

// ---------------- build phase (once per call) --------------------------------
__global__ __launch_bounds__(256) void build1_kernel(
    const int* __restrict__ ei, int* __restrict__ cnt, int* __restrict__ posArr)
{
    int e = blockIdx.x * 256 + threadIdx.x;
    if (e < NE) posArr[e] = atomicAdd(&cnt[ei[e]], 1);
}

__global__ __launch_bounds__(SCAN_B) void scan1_kernel(
    const int* __restrict__ cnt, int* __restrict__ bsum)
{
    int i = blockIdx.x * SCAN_B + threadIdx.x;
    int v = (i < NN) ? cnt[i] : 0;
#pragma unroll
    for (int off = 32; off > 0; off >>= 1) v += __shfl_down(v, off, 64);
    __shared__ int wsum[16];
    int wave = threadIdx.x >> 6, lane = threadIdx.x & 63;
    if (lane == 0) wsum[wave] = v;
    __syncthreads();
    if (threadIdx.x == 0) {
        int s = 0;
#pragma unroll
        for (int w = 0; w < 16; w++) s += wsum[w];
        bsum[blockIdx.x] = s;
    }
}

__global__ void scan2_kernel(const int* __restrict__ bsum, int* __restrict__ bexcl,
                             int* __restrict__ off)
{
    if (threadIdx.x == 0 && blockIdx.x == 0) {
        int s = 0;
        for (int b = 0; b < NBLK_SCAN; b++) { bexcl[b] = s; s += bsum[b]; }
        off[NN] = s;
    }
}

// off aliases cnt: each block reads its own cnt range, then overwrites with off.
// (per-block disjoint ranges; read happens before write within each thread)
__global__ __launch_bounds__(SCAN_B) void scan3_kernel(
    const int* cnt, const int* __restrict__ bexcl, int* off)
{
    __shared__ int buf[2][SCAN_B];
    int t = threadIdx.x;
    int i = blockIdx.x * SCAN_B + t;
    int v = (i < NN) ? cnt[i] : 0;
    buf[0][t] = v;
    __syncthreads();
    int src = 0;
    for (int d = 1; d < SCAN_B; d <<= 1) {
        int nv = buf[src][t] + ((t >= d) ? buf[src][t - d] : 0);
        buf[src ^ 1][t] = nv;
        src ^= 1;
        __syncthreads();
    }
    if (i < NN) off[i] = bexcl[blockIdx.x] + buf[src][t] - v;   // exclusive
}

// materialize row-sorted edges: packed int2 {row,col} + sorted eattr (L0 input)
__global__ __launch_bounds__(256) void fill2_kernel(
    const int* __restrict__ ei, const int* __restrict__ posArr,
    const int* __restrict__ off, const float* __restrict__ eattr,
    int2* __restrict__ edata, float2* __restrict__ ea_sorted)
{
    int e = blockIdx.x * 256 + threadIdx.x;
    if (e < NE) {
        int row = ei[e];
        int j = off[row] + posArr[e];
        edata[j] = make_int2(row, ei[NE + e]);
        ea_sorted[j] = reinterpret_cast<const float2*>(eattr)[e];
    }
}

// ---------------- edge block: MLP(19->16->2), 2 edges/thread -----------------
// Weights via uniform scalar path (SGPR broadcast); edata packed int2;
// per-layer edge attrs come from `ein` (sorted eattr for L0, prev eout after).
template <bool NEED_SUM>
__global__ __launch_bounds__(256) void edge_kernel(
    const int2* __restrict__ edata, const float* __restrict__ x,
    const float* __restrict__ ein, const float* __restrict__ gptr,
    const float* __restrict__ W1, const float* __restrict__ B1,
    const float* __restrict__ W2, const float* __restrict__ B2,
    float* __restrict__ eout, float* __restrict__ esum)
{
    int j0 = blockIdx.x * 256 + threadIdx.x;     // grid exact: NEH/256
    int j1 = j0 + NEH;

    float gval = gptr[0];

    int2 dA = edata[j0];
    int2 dB = edata[j1];

    float inA[19], inB[19];
    inA[0] = gval; inB[0] = gval;
    {
        const float4* p = reinterpret_cast<const float4*>(x + (size_t)dA.x * 8);
        float4 a0 = p[0], a1 = p[1];
        inA[1] = a0.x; inA[2] = a0.y; inA[3] = a0.z; inA[4] = a0.w;
        inA[5] = a1.x; inA[6] = a1.y; inA[7] = a1.z; inA[8] = a1.w;
    }
    {
        const float4* p = reinterpret_cast<const float4*>(x + (size_t)dA.y * 8);
        float4 a0 = p[0], a1 = p[1];
        inA[9] = a0.x; inA[10] = a0.y; inA[11] = a0.z; inA[12] = a0.w;
        inA[13] = a1.x; inA[14] = a1.y; inA[15] = a1.z; inA[16] = a1.w;
    }
    {
        const float4* p = reinterpret_cast<const float4*>(x + (size_t)dB.x * 8);
        float4 a0 = p[0], a1 = p[1];
        inB[1] = a0.x; inB[2] = a0.y; inB[3] = a0.z; inB[4] = a0.w;
        inB[5] = a1.x; inB[6] = a1.y; inB[7] = a1.z; inB[8] = a1.w;
    }
    {
        const float4* p = reinterpret_cast<const float4*>(x + (size_t)dB.y * 8);
        float4 a0 = p[0], a1 = p[1];
        inB[9] = a0.x; inB[10] = a0.y; inB[11] = a0.z; inB[12] = a0.w;
        inB[13] = a1.x; inB[14] = a1.y; inB[15] = a1.z; inB[16] = a1.w;
    }
    {
        float2 ea = reinterpret_cast<const float2*>(ein)[j0];
        inA[17] = ea.x; inA[18] = ea.y;
        float2 eb = reinterpret_cast<const float2*>(ein)[j1];
        inB[17] = eb.x; inB[18] = eb.y;
    }

    float hA[16], hB[16];
#pragma unroll
    for (int q = 0; q < 16; q++) { float b = B1[q]; hA[q] = b; hB[q] = b; }
#pragma unroll
    for (int k = 0; k < 19; k++) {
        float vA = inA[k], vB = inB[k];
#pragma unroll
        for (int q = 0; q < 16; q++) {
            float w = W1[k * 16 + q];          // uniform -> s_load + broadcast
            hA[q] += vA * w;
            hB[q] += vB * w;
        }
    }
    float oA0 = B2[0], oA1 = B2[1], oB0 = B2[0], oB1 = B2[1];
#pragma unroll
    for (int q = 0; q < 16; q++) {
        float w0 = W2[2 * q], w1 = W2[2 * q + 1];
        float a = fmaxf(hA[q], 0.f);
        float b = fmaxf(hB[q], 0.f);
        oA0 += a * w0; oA1 += a * w1;
        oB0 += b * w0; oB1 += b * w1;
    }
    reinterpret_cast<float2*>(eout)[j0] = make_float2(oA0, oA1);
    reinterpret_cast<float2*>(eout)[j1] = make_float2(oB0, oB1);

    if (NEED_SUM) {
        float r0 = wave_red(oA0 + oB0);
        float r1 = wave_red(oA1 + oB1);
        __shared__ float red[4][2];
        int wave = threadIdx.x >> 6, lane = threadIdx.x & 63;
        if (lane == 0) { red[wave][0] = r0; red[wave][1] = r1; }
        __syncthreads();
        if (threadIdx.x == 0) {
            float s0 = red[0][0] + red[1][0] + red[2][0] + red[3][0];
            float s1 = red[0][1] + red[1][1] + red[2][1] + red[3][1];
            atomicAdd(&esum[0], s0);
            atomicAdd(&esum[1], s1);
        }
    }
}

// -------- node block: contiguous-range aggregate + MLP(11->16->8) ------------
template <bool NEED_SUM>
__global__ __launch_bounds__(256) void node_kernel(
    const float* __restrict__ x, const float* __restrict__ eout,
    const int* __restrict__ off, const float* __restrict__ gptr,
    const float* __restrict__ W1, const float* __restrict__ B1,
    const float* __restrict__ W2, const float* __restrict__ B2,
    float* __restrict__ xout, float* __restrict__ nsum)
{
    int i = blockIdx.x * 256 + threadIdx.x;
    float out[8];
#pragma unroll
    for (int m = 0; m < 8; m++) out[m] = 0.f;

    if (i < NN) {
        float in[11];
        in[0] = gptr[0];
        const float4* xi = reinterpret_cast<const float4*>(x + (size_t)i * 8);
        float4 a0 = xi[0], a1 = xi[1];
        in[1] = a0.x; in[2] = a0.y; in[3] = a0.z; in[4] = a0.w;
        in[5] = a1.x; in[6] = a1.y; in[7] = a1.z; in[8] = a1.w;

        int b0 = off[i], b1 = off[i + 1];
        const float2* e2 = reinterpret_cast<const float2*>(eout);
        const float4* e4 = reinterpret_cast<const float4*>(eout);
        float s0 = 0.f, s1 = 0.f;
        int j = b0;
        if ((j & 1) && j < b1) { float2 v = e2[j]; s0 += v.x; s1 += v.y; j++; }
        for (; j + 2 <= b1; j += 2) {
            float4 v = e4[j >> 1];
            s0 += v.x + v.z; s1 += v.y + v.w;
        }
        if (j < b1) { float2 v = e2[j]; s0 += v.x; s1 += v.y; }
        in[9] = s0; in[10] = s1;

        float h[16];
#pragma unroll
        for (int q = 0; q < 16; q++) h[q] = B1[q];
#pragma unroll
        for (int k = 0; k < 11; k++) {
            float v = in[k];
#pragma unroll
            for (int q = 0; q < 16; q++) h[q] += v * W1[k * 16 + q];
        }
#pragma unroll
        for (int m = 0; m < 8; m++) out[m] = B2[m];
#pragma unroll
        for (int q = 0; q < 16; q++) {
            float hq = fmaxf(h[q], 0.f);
#pragma unroll
            for (int m = 0; m < 8; m++) out[m] += hq * W2[q * 8 + m];
        }
        float4* xo = reinterpret_cast<float4*>(xout + (size_t)i * 8);
        xo[0] = make_float4(out[0], out[1], out[2], out[3]);
        xo[1] = make_float4(out[4], out[5], out[6], out[7]);
    }
    if (NEED_SUM) {
        float r[8];
#pragma unroll
        for (int m = 0; m < 8; m++) r[m] = wave_red(out[m]);
        __shared__ float red[4][8];
        int wave = threadIdx.x >> 6, lane = threadIdx.x & 63;
        if (lane == 0) {
#pragma unroll
            for (int m = 0; m < 8; m++) red[wave][m] = r[m];
        }
        __syncthreads();
        if (threadIdx.x == 0) {
#pragma unroll
            for (int m = 0; m < 8; m++) {
                float s = red[0][m] + red[1][m] + red[2][m] + red[3][m];
                atomicAdd(&nsum[m], s);
            }
        }
    }
}

// ---------------- global block: MLP(11->16->1), single thread ----------------
__global__ void glob_kernel(const float* __restrict__ esum, const float* __restrict__ nsum,
                            const float* __restrict__ gold,
                            const float* __restrict__ W1, const float* __restrict__ B1,
                            const float* __restrict__ W2, const float* __restrict__ B2,
                            float* __restrict__ gnew)
{
    if (threadIdx.x == 0 && blockIdx.x == 0) {
        float in[11];
#pragma unroll
        for (int j = 0; j < 8; j++) in[j] = nsum[j] * (1.0f / NN);
        in[8] = esum[0] * (1.0f / NE);
        in[9] = esum[1] * (1.0f / NE);
        in[10] = gold[0];
        float acc = B2[0];
#pragma unroll
        for (int j = 0; j < 16; j++) {
            float h = B1[j];
#pragma unroll
            for (int k = 0; k < 11; k++) h += in[k] * W1[k * 16 + j];
            acc += fmaxf(h, 0.f) * W2[j];
        }
        gnew[0] = acc;
    }
}

extern "C" void kernel_launch(void* const* d_in, const int* in_sizes, int n_in,
                              void* d_out, int out_size, void* d_ws, size_t ws_size,
                              hipStream_t stream) {
    const float* x     = (const float*)d_in[0];
    const int*   ei    = (const int*)d_in[1];
    const float* eattr = (const float*)d_in[2];
    const float* g     = (const float*)d_in[3];
    const float* eW1 = (const float*)d_in[4];
    const float* eB1 = (const float*)d_in[5];
    const float* eW2 = (const float*)d_in[6];
    const float* eB2 = (const float*)d_in[7];
    const float* nW1 = (const float*)d_in[8];
    const float* nB1 = (const float*)d_in[9];
    const float* nW2 = (const float*)d_in[10];
    const float* nB2 = (const float*)d_in[11];
    const float* gW1 = (const float*)d_in[12];
    const float* gB1 = (const float*)d_in[13];
    const float* gW2 = (const float*)d_in[14];
    const float* gB2 = (const float*)d_in[15];
    float* out = (float*)d_out;

    char* ws = (char*)d_ws;
    float*  xb0    = (float*)(ws);                 // 3,200,000
    float*  xb1    = (float*)(ws + 3200000);       // 3,200,000
    int*    off    = (int*)  (ws + 6400000);       // (NN+1)*4 (aliases cnt)
    int*    cnt    = off;
    int*    bsum   = (int*)  (ws + 6800016);       // 392
    int*    bexcl  = (int*)  (ws + 6800416);       // 392
    float*  esum   = (float*)(ws + 6800816);       // 2 floats
    float*  nsum   = (float*)(ws + 6800848);       // 8 floats
    float*  g1     = (float*)(ws + 6800880);
    float*  g2     = g1 + 1;
    float*  eb0    = (float*)(ws + 6800896);       // 12,800,000
    float*  eb1    = (float*)(ws + 19600896);      // 12,800,000 (also sorted eattr, L0 input)
    int*    posArr = (int*)  (ws + 32400896);      // 6,400,000
    int2*   edata  = (int2*) (ws + 38800896);      // 12,800,000 -> ends 51,600,896

    dim3 blk(256);
    dim3 egrid(NE / 256);                          // 6250 (build/fill)
    dim3 e2grid(NEH / 256);                        // 3125 (edge MLP, 2 edges/thread)
    dim3 ngrid((NN + 255) / 256);                  // 391

    // ---- build row-sorted packed CSR (once per call) ----
    hipMemsetAsync(cnt, 0, 400000, stream);
    hipMemsetAsync(esum, 0, 64, stream);           // esum + nsum
    build1_kernel<<<egrid, blk, 0, stream>>>(ei, cnt, posArr);
    scan1_kernel<<<NBLK_SCAN, SCAN_B, 0, stream>>>(cnt, bsum);
    scan2_kernel<<<1, 64, 0, stream>>>(bsum, bexcl, off);
    scan3_kernel<<<NBLK_SCAN, SCAN_B, 0, stream>>>(cnt, bexcl, off);
    fill2_kernel<<<egrid, blk, 0, stream>>>(ei, posArr, off, eattr,
        edata, (float2*)eb1);

    // ---- layer 0: edge attrs = sorted eattr (eb1) -> eout eb0 ----
    edge_kernel<true><<<e2grid, blk, 0, stream>>>(edata, x, eb1, g,
        eW1, eB1, eW2, eB2, eb0, esum);
    node_kernel<true><<<ngrid, blk, 0, stream>>>(x, eb0, off, g,
        nW1, nB1, nW2, nB2, xb0, nsum);
    glob_kernel<<<1, 64, 0, stream>>>(esum, nsum, g, gW1, gB1, gW2, gB2, g1);

    // ---- layer 1: edge attrs = L0 edge emb (eb0) -> eout eb1 ----
    hipMemsetAsync(esum, 0, 64, stream);
    edge_kernel<true><<<e2grid, blk, 0, stream>>>(edata, xb0, eb0, g1,
        eW1 + 304, eB1 + 16, eW2 + 32, eB2 + 2, eb1, esum);
    node_kernel<true><<<ngrid, blk, 0, stream>>>(xb0, eb1, off, g1,
        nW1 + 176, nB1 + 16, nW2 + 128, nB2 + 8, xb1, nsum);
    glob_kernel<<<1, 64, 0, stream>>>(esum, nsum, g1, gW1 + 176, gB1 + 16, gW2 + 16, gB2 + 1, g2);

    // ---- layer 2: edge attrs = L1 edge emb (eb1) -> eout eb0; out -> d_out --
    edge_kernel<false><<<e2grid, blk, 0, stream>>>(edata, xb1, eb1, g2,
        eW1 + 608, eB1 + 32, eW2 + 64, eB2 + 4, eb0, esum);
    node_kernel<false><<<ngrid, blk, 0, stream>>>(xb1, eb0, off, g2,
        nW1 + 352, nB1 + 32, nW2 + 256, nB2 + 16, out, nsum);
}